// Round 10
// baseline (441.645 us; speedup 1.0000x reference)
//
#include <hip/hip_runtime.h>

typedef short s8v  __attribute__((ext_vector_type(8)));
typedef float f4v  __attribute__((ext_vector_type(4)));

#define B_   512
#define C_   3
#define N_   128
#define F_   256
#define T_   256
#define HID_ 128
#define G3_  384

__device__ __forceinline__ ushort f2bf(float f) {
  union { float f; unsigned u; } v; v.f = f;
  return (ushort)((v.u + 0x7FFFu + ((v.u >> 16) & 1u)) >> 16);
}
__device__ __forceinline__ float bf2f(ushort h) {
  union { unsigned u; float f; } v; v.u = ((unsigned)h) << 16;
  return v.f;
}
__device__ __forceinline__ float rcp_(float x) { return __builtin_amdgcn_rcpf(x); }
__device__ __forceinline__ float sigm(float x) { return rcp_(1.0f + __expf(-x)); }
__device__ __forceinline__ float tanh_(float x) { return 2.0f * rcp_(1.0f + __expf(-2.0f * x)) - 1.0f; }

// barrier that waits only LDS ops (no vmcnt drain: stores/prefetch stay in flight)
#define LDS_BARRIER() asm volatile("s_waitcnt lgkmcnt(0)\n\ts_barrier" ::: "memory")

// ---------------- weight fp32 -> bf16 (row-major [384][128] x 4) ----------------
__global__ void k_wcvt(const float* __restrict__ a, const float* __restrict__ b,
                       const float* __restrict__ c, const float* __restrict__ d,
                       ushort* __restrict__ o) {
  int i = blockIdx.x * 256 + threadIdx.x;          // 4*49152 = 196608 exact
  const float* src = (i < 49152) ? a : (i < 98304) ? b : (i < 147456) ? c : d;
  o[i] = f2bf(src[i % 49152]);
}

// ---------------- Hn[n][m] = dinv[n]*H'(diag=1)[n][m]*dinv[m] -> bf16, fully parallel ----------------
__global__ __launch_bounds__(256) void k_hnorm(const float* __restrict__ H,
                                               ushort* __restrict__ Hn) {
  __shared__ float dvr[N_];
  const int bc = blockIdx.x;                       // 0..1535 = b*3+c
  const int tid = threadIdx.x;
  const int r = tid >> 1;                          // row 0..127
  const int half = (tid & 1) * 64;                 // col half
  const float* src = H + (size_t)bc * N_ * N_ + (size_t)r * N_ + half;

  float v[64];
  #pragma unroll
  for (int i = 0; i < 16; ++i) {
    float4 q = *(const float4*)&src[i * 4];
    v[i * 4 + 0] = q.x; v[i * 4 + 1] = q.y; v[i * 4 + 2] = q.z; v[i * 4 + 3] = q.w;
  }
  if ((r >> 6) == (tid & 1)) v[r & 63] = 1.0f;     // diagonal -> 1
  float s = 0.f;
  #pragma unroll
  for (int i = 0; i < 64; ++i) s += v[i];
  s += __shfl_xor(s, 1);                           // pair holds full row sum
  if ((tid & 1) == 0) dvr[r] = 1.0f / sqrtf(s);
  __syncthreads();

  const float dr = dvr[r];
  ushort* dst = Hn + (size_t)bc * N_ * N_ + (size_t)r * N_ + half;
  #pragma unroll
  for (int i4 = 0; i4 < 16; ++i4) {
    float4 dc = *(const float4*)&dvr[half + i4 * 4];
    ushort4 o;
    o.x = f2bf(v[i4 * 4 + 0] * dr * dc.x);
    o.y = f2bf(v[i4 * 4 + 1] * dr * dc.y);
    o.z = f2bf(v[i4 * 4 + 2] * dr * dc.z);
    o.w = f2bf(v[i4 * 4 + 3] * dr * dc.w);
    *(ushort4*)&dst[i4 * 4] = o;
  }
}

// ---------------- gcn_conv GEMM + leaky + soft-sum -> XcT[b*256+t][n] bf16 ----------------
// Hn pre-scaled; leaky(wmul*v) with wmul>0, dinv>0 folds scales freely.
__global__ __launch_bounds__(256, 2) void k_conv2(
    const float* __restrict__ X, const ushort* __restrict__ Hn,
    const float* __restrict__ wscal, const float* __restrict__ soft,
    ushort* __restrict__ XcT) {
  __shared__ ushort hc[N_][136];       // one channel's Hn tile
  __shared__ ushort xt[N_][136];       // X^T[f][m] one f-half; reused as out staging
  const int b = blockIdx.x;
  const int tid = threadIdx.x;
  const int lane = tid & 63, w = tid >> 6;
  const int rq = lane >> 4, l15 = lane & 15;
  const float wmul = wscal[0];
  const float scf[3] = {soft[0], soft[1], soft[2]};
  const ushort* Hb = Hn + (size_t)b * C_ * N_ * N_;
  const int srow = tid >> 1;                   // staging: row, col-half
  const int scol = (tid & 1) * 64;

  for (int fh = 0; fh < 2; ++fh) {
    __syncthreads();                 // xt free (prev writeout reads done)
    {
      const int fl4 = (tid & 31) * 4;
      const int mof = tid >> 5;
      #pragma unroll
      for (int p = 0; p < 16; ++p) {
        int m = p * 8 + mof;
        float4 v = *(const float4*)&X[((size_t)b * N_ + m) * F_ + fh * 128 + fl4];
        xt[fl4 + 0][m] = f2bf(v.x);
        xt[fl4 + 1][m] = f2bf(v.y);
        xt[fl4 + 2][m] = f2bf(v.z);
        xt[fl4 + 3][m] = f2bf(v.w);
      }
    }
    __syncthreads();

    s8v af[2][4];
    #pragma unroll
    for (int rt = 0; rt < 2; ++rt)
      #pragma unroll
      for (int kk = 0; kk < 4; ++kk)
        af[rt][kk] = *(const s8v*)&xt[w * 32 + rt * 16 + l15][kk * 32 + rq * 8];

    f4v xc[2][8];
    #pragma unroll
    for (int rt = 0; rt < 2; ++rt)
      #pragma unroll
      for (int nt = 0; nt < 8; ++nt)
        xc[rt][nt] = (f4v){0.f, 0.f, 0.f, 0.f};

    for (int c = 0; c < C_; ++c) {
      __syncthreads();               // prev c's MFMA reads of hc done
      {
        const ushort* hsrc = &Hb[((size_t)c * N_ + srow) * N_ + scol];
        #pragma unroll
        for (int p = 0; p < 8; ++p)
          *(s8v*)&hc[srow][scol + p * 8] = *(const s8v*)&hsrc[p * 8];
      }
      __syncthreads();

      f4v hx[2][8];
      #pragma unroll
      for (int rt = 0; rt < 2; ++rt)
        #pragma unroll
        for (int nt = 0; nt < 8; ++nt)
          hx[rt][nt] = (f4v){0.f, 0.f, 0.f, 0.f};
      #pragma unroll
      for (int kk = 0; kk < 4; ++kk) {
        #pragma unroll
        for (int nt = 0; nt < 8; ++nt) {
          s8v bf = *(const s8v*)&hc[nt * 16 + l15][kk * 32 + rq * 8];
          hx[0][nt] = __builtin_amdgcn_mfma_f32_16x16x32_bf16(af[0][kk], bf, hx[0][nt], 0, 0, 0);
          hx[1][nt] = __builtin_amdgcn_mfma_f32_16x16x32_bf16(af[1][kk], bf, hx[1][nt], 0, 0, 0);
        }
      }
      const float s = scf[c];
      #pragma unroll
      for (int nt = 0; nt < 8; ++nt) {
        #pragma unroll
        for (int i = 0; i < 4; ++i) {
          float v0 = hx[0][nt][i] * wmul;
          xc[0][nt][i] += s * fmaxf(v0, 0.01f * v0);
          float v1 = hx[1][nt][i] * wmul;
          xc[1][nt][i] += s * fmaxf(v1, 0.01f * v1);
        }
      }
    }
    __syncthreads();                 // all xt A-frag reads long done; reuse as staging
    #pragma unroll
    for (int rt = 0; rt < 2; ++rt)
      #pragma unroll
      for (int nt = 0; nt < 8; ++nt)
        #pragma unroll
        for (int i = 0; i < 4; ++i)
          xt[w * 32 + rt * 16 + rq * 4 + i][nt * 16 + l15] = f2bf(xc[rt][nt][i]);
    __syncthreads();
    #pragma unroll
    for (int p = 0; p < 4; ++p) {
      int tl = p * 32 + (tid >> 3);
      int n0 = (tid & 7) * 16;
      size_t rowb = ((size_t)b * F_ + fh * 128 + tl) * N_;
      *(s8v*)&XcT[rowb + n0]     = *(const s8v*)&xt[tl][n0];
      *(s8v*)&XcT[rowb + n0 + 8] = *(const s8v*)&xt[tl][n0 + 8];
    }
  }
}

// ---------------- bidirectional GRU (R5 proven structure, bf16 weight buffer) ----------------
__global__ __launch_bounds__(512, 2) void k_gru(
    const ushort* __restrict__ XcT, const ushort* __restrict__ wbf,
    const float* __restrict__ bihf, const float* __restrict__ bhhf,
    const float* __restrict__ bihb, const float* __restrict__ bhhb,
    ushort* __restrict__ y) {
  __shared__ ushort hlds[2][16][136];
  __shared__ ushort xbuf[2][16][136];
  const int dir = blockIdx.x >> 5;
  const int chunk = blockIdx.x & 31;
  const int tid = threadIdx.x;
  const int lane = tid & 63, w = tid >> 6;
  const int rq = lane >> 4, l15 = lane & 15;
  const int jb = w * 16;
  const int jr = jb + rq * 4;
  const ushort* wih = wbf + (size_t)(dir * 2) * G3_ * HID_;
  const ushort* whh = wih + G3_ * HID_;
  const float* bih = dir ? bihb : bihf;
  const float* bhh = dir ? bhhb : bhhf;

  s8v fir[4], fiz[4], fin[4], fhr[4], fhz[4], fhn[4];
  #pragma unroll
  for (int kk = 0; kk < 4; ++kk) {
    const int ko = kk * 32 + rq * 8;
    const int row = jb + l15;
    fir[kk] = *(const s8v*)&wih[(size_t)(row)       * HID_ + ko];
    fiz[kk] = *(const s8v*)&wih[(size_t)(128 + row) * HID_ + ko];
    fin[kk] = *(const s8v*)&wih[(size_t)(256 + row) * HID_ + ko];
    fhr[kk] = *(const s8v*)&whh[(size_t)(row)       * HID_ + ko];
    fhz[kk] = *(const s8v*)&whh[(size_t)(128 + row) * HID_ + ko];
    fhn[kk] = *(const s8v*)&whh[(size_t)(256 + row) * HID_ + ko];
  }
  float4 bi_r = *(const float4*)&bih[jr],        bh_r = *(const float4*)&bhh[jr];
  float4 bi_z = *(const float4*)&bih[128 + jr],  bh_z = *(const float4*)&bhh[128 + jr];
  float4 bin4 = *(const float4*)&bih[256 + jr];
  float4 bhn4 = *(const float4*)&bhh[256 + jr];
  f4v br = {bi_r.x + bh_r.x, bi_r.y + bh_r.y, bi_r.z + bh_r.z, bi_r.w + bh_r.w};
  f4v bz = {bi_z.x + bh_z.x, bi_z.y + bh_z.y, bi_z.z + bh_z.z, bi_z.w + bh_z.w};
  f4v bin = {bin4.x, bin4.y, bin4.z, bin4.w};
  f4v bhn = {bhn4.x, bhn4.y, bhn4.z, bhn4.w};

  for (int i = tid; i < 16 * 136; i += 512) ((ushort*)hlds[0])[i] = 0;

  const int rr = tid >> 5;
  const int nq = (tid & 31) * 4;
  const size_t xrow = (size_t)(chunk * 16 + rr) * T_;
  {
    int t0 = dir ? (T_ - 1) : 0;
    *(ushort4*)&xbuf[0][rr][nq] = *(const ushort4*)&XcT[(xrow + t0) * N_ + nq];
  }
  f4v hreg = {0.f, 0.f, 0.f, 0.f};
  __syncthreads();

  for (int s = 0; s < T_; ++s) {
    const int cur = s & 1;
    const int t_in = dir ? (T_ - 1 - s) : s;
    const int sn = (s + 1 < T_) ? s + 1 : s;
    const int t_nx = dir ? (T_ - 1 - sn) : sn;
    ushort4 xn = *(const ushort4*)&XcT[(xrow + t_nx) * N_ + nq];

    f4v ar = br, az = bz, ain = bin, ahn = bhn;
    #pragma unroll
    for (int kk = 0; kk < 4; ++kk) {
      const int ko = kk * 32 + rq * 8;
      s8v xf = *(const s8v*)&xbuf[cur][l15][ko];
      s8v hf = *(const s8v*)&hlds[cur][l15][ko];
      ar  = __builtin_amdgcn_mfma_f32_16x16x32_bf16(fir[kk], xf, ar, 0, 0, 0);
      ar  = __builtin_amdgcn_mfma_f32_16x16x32_bf16(fhr[kk], hf, ar, 0, 0, 0);
      az  = __builtin_amdgcn_mfma_f32_16x16x32_bf16(fiz[kk], xf, az, 0, 0, 0);
      az  = __builtin_amdgcn_mfma_f32_16x16x32_bf16(fhz[kk], hf, az, 0, 0, 0);
      ain = __builtin_amdgcn_mfma_f32_16x16x32_bf16(fin[kk], xf, ain, 0, 0, 0);
      ahn = __builtin_amdgcn_mfma_f32_16x16x32_bf16(fhn[kk], hf, ahn, 0, 0, 0);
    }
    ushort hb[4];
    #pragma unroll
    for (int i = 0; i < 4; ++i) {
      float r = sigm(ar[i]);
      float z = sigm(az[i]);
      float n = tanh_(ain[i] + r * ahn[i]);
      float h = n + z * (hreg[i] - n);
      hreg[i] = h;
      hb[i] = f2bf(h);
    }
    ushort4 hv; hv.x = hb[0]; hv.y = hb[1]; hv.z = hb[2]; hv.w = hb[3];
    *(ushort4*)&y[((size_t)t_in * B_ + chunk * 16 + l15) * 256 + dir * 128 + jr] = hv;
    *(ushort4*)&hlds[cur ^ 1][l15][jr] = hv;
    *(ushort4*)&xbuf[cur ^ 1][rr][nq] = xn;
    LDS_BARRIER();
  }
}

// ---------------- BN stats per t-channel over (b,j): fold gamma/beta ----------------
__global__ void k_stats(const ushort* __restrict__ y, const float* __restrict__ gamma,
                        const float* __restrict__ beta, float* __restrict__ stats) {
  const int t = blockIdx.x, tid = threadIdx.x;
  const ushort* p = y + (size_t)t * 256 * B_;
  float s = 0.f, q = 0.f;
  for (int i = tid * 8; i < 256 * B_; i += 256 * 8) {
    s8v v = *(const s8v*)&p[i];
    #pragma unroll
    for (int e = 0; e < 8; ++e) {
      float f = bf2f((ushort)v[e]);
      s += f; q += f * f;
    }
  }
  #pragma unroll
  for (int o = 32; o; o >>= 1) { s += __shfl_xor(s, o); q += __shfl_xor(q, o); }
  __shared__ float rs[4], rq2[4];
  if ((tid & 63) == 0) { rs[tid >> 6] = s; rq2[tid >> 6] = q; }
  __syncthreads();
  if (tid == 0) {
    s = rs[0] + rs[1] + rs[2] + rs[3];
    q = rq2[0] + rq2[1] + rq2[2] + rq2[3];
    const float inv = 1.0f / (256.f * 512.f);
    float mean = s * inv;
    float var = q * inv - mean * mean;
    float istd = 1.0f / sqrtf(var + 1e-5f);
    float a = gamma[t] * istd;
    stats[2 * t] = a;
    stats[2 * t + 1] = beta[t] - mean * a;
  }
}

// ---------------- BN apply + transpose: y[t][b][j] -> out[b][j][t] fp32 ----------------
__global__ __launch_bounds__(256) void k_apply(
    const ushort* __restrict__ y, const float* __restrict__ stats,
    float* __restrict__ out) {
  __shared__ ushort tile[256][64];     // [t][64 j], 16B chunks XOR-swizzled by t
  __shared__ float sA[256], sB[256];
  const int b = blockIdx.x;
  const int j0 = blockIdx.y * 64;
  const int tid = threadIdx.x;
  sA[tid] = stats[2 * tid];
  sB[tid] = stats[2 * tid + 1];
  {
    const ushort* src = &y[((size_t)tid * B_ + b) * 256 + j0];
    const int sw = (tid >> 5) & 7;
    #pragma unroll
    for (int q = 0; q < 8; ++q)
      *(s8v*)&tile[tid][(q ^ sw) * 8] = *(const s8v*)&src[q * 8];
  }
  __syncthreads();
  const int j = tid >> 2, jc = j >> 3, jrr = j & 7;
  const int tq = tid & 3;
  float* op = out + ((size_t)b * 256 + j0 + j) * 256 + tq * 64;
  #pragma unroll
  for (int k = 0; k < 16; ++k) {
    const int t = tq * 64 + k * 4;
    float4 o;
    #pragma unroll
    for (int e = 0; e < 4; ++e) {
      const int te = t + e;
      const int sw2 = (te >> 5) & 7;
      const int jcol = ((jc ^ sw2) * 8) + jrr;
      float vv = bf2f(tile[te][jcol]) * sA[te] + sB[te];
      if (e == 0) o.x = vv; else if (e == 1) o.y = vv; else if (e == 2) o.z = vv; else o.w = vv;
    }
    *(float4*)&op[k * 4] = o;
  }
}

extern "C" void kernel_launch(void* const* d_in, const int* in_sizes, int n_in,
                              void* d_out, int out_size, void* d_ws, size_t ws_size,
                              hipStream_t stream) {
  const float* X      = (const float*)d_in[0];
  const float* H      = (const float*)d_in[1];
  const float* weight = (const float*)d_in[2];
  const float* soft   = (const float*)d_in[3];
  const float* w_ih_f = (const float*)d_in[4];
  const float* w_hh_f = (const float*)d_in[5];
  const float* b_ih_f = (const float*)d_in[6];
  const float* b_hh_f = (const float*)d_in[7];
  const float* w_ih_b = (const float*)d_in[8];
  const float* w_hh_b = (const float*)d_in[9];
  const float* b_ih_b = (const float*)d_in[10];
  const float* b_hh_b = (const float*)d_in[11];
  const float* gamma  = (const float*)d_in[12];
  const float* beta   = (const float*)d_in[13];
  float* out = (float*)d_out;

  char* ws = (char*)d_ws;
  ushort* wbf   = (ushort*)(ws);                        // 393,216 B
  ushort* Hnb   = (ushort*)(ws + 393216);               // 50,331,648 B
  ushort* XcT   = (ushort*)(ws + 50724864);             // 33,554,432 B
  ushort* ybuf  = (ushort*)(ws + 84279296);             // 67,108,864 B  [t][b][j]
  float*  stats = (float*) (ws + 151388160);            // 2,048 B

  k_wcvt<<<768, 256, 0, stream>>>(w_ih_f, w_hh_f, w_ih_b, w_hh_b, wbf);
  k_hnorm<<<B_ * C_, 256, 0, stream>>>(H, Hnb);
  k_conv2<<<B_, 256, 0, stream>>>(X, Hnb, weight, soft, XcT);
  k_gru<<<64, 512, 0, stream>>>(XcT, wbf, b_ih_f, b_hh_f, b_ih_b, b_hh_b, ybuf);
  k_stats<<<T_, 256, 0, stream>>>(ybuf, gamma, beta, stats);
  k_apply<<<dim3(512, 4), 256, 0, stream>>>(ybuf, stats, out);
}

// Round 11
// 360.767 us; speedup vs baseline: 1.2242x; 1.2242x over previous
//
#include <hip/hip_runtime.h>

typedef short s8v  __attribute__((ext_vector_type(8)));
typedef float f4v  __attribute__((ext_vector_type(4)));

#define B_   512
#define C_   3
#define N_   128
#define F_   256
#define T_   256
#define HID_ 128
#define G3_  384

__device__ __forceinline__ ushort f2bf(float f) {
  union { float f; unsigned u; } v; v.f = f;
  return (ushort)((v.u + 0x7FFFu + ((v.u >> 16) & 1u)) >> 16);
}
__device__ __forceinline__ float bf2f(ushort h) {
  union { unsigned u; float f; } v; v.u = ((unsigned)h) << 16;
  return v.f;
}
__device__ __forceinline__ float rcp_(float x) { return __builtin_amdgcn_rcpf(x); }
__device__ __forceinline__ float sigm(float x) { return rcp_(1.0f + __expf(-x)); }
__device__ __forceinline__ float tanh_(float x) { return 2.0f * rcp_(1.0f + __expf(-2.0f * x)) - 1.0f; }

// barrier that waits only LDS ops (no vmcnt drain: stores/prefetch stay in flight)
#define LDS_BARRIER() asm volatile("s_waitcnt lgkmcnt(0)\n\ts_barrier" ::: "memory")

// ---------------- weight fp32 -> bf16 (row-major [384][128] x 4) ----------------
__global__ void k_wcvt(const float* __restrict__ a, const float* __restrict__ b,
                       const float* __restrict__ c, const float* __restrict__ d,
                       ushort* __restrict__ o) {
  int i = blockIdx.x * 256 + threadIdx.x;          // 4*49152 = 196608 exact
  const float* src = (i < 49152) ? a : (i < 98304) ? b : (i < 147456) ? c : d;
  o[i] = f2bf(src[i % 49152]);
}

// ---------------- Hn[n][m] = dinv[n]*H'(diag=1)[n][m]*dinv[m] -> bf16 ----------------
// Branchless diag (compile-time indices only -> no scratch). 512 thr, v[32] in regs.
__global__ __launch_bounds__(512) void k_hnorm(const float* __restrict__ H,
                                               ushort* __restrict__ Hn) {
  __shared__ float dvr[N_];
  const int bc = blockIdx.x;                       // 0..1535 = b*3+c
  const int tid = threadIdx.x;
  const int r = tid >> 2;                          // row 0..127
  const int q0 = (tid & 3) * 32;                   // col quarter
  const float* src = H + (size_t)bc * 16384 + (size_t)r * 128 + q0;

  float v[32];
  #pragma unroll
  for (int i = 0; i < 8; ++i) {
    float4 t4 = *(const float4*)&src[i * 4];
    const int c = q0 + i * 4;
    v[i * 4 + 0] = (c + 0 == r) ? 1.0f : t4.x;
    v[i * 4 + 1] = (c + 1 == r) ? 1.0f : t4.y;
    v[i * 4 + 2] = (c + 2 == r) ? 1.0f : t4.z;
    v[i * 4 + 3] = (c + 3 == r) ? 1.0f : t4.w;
  }
  float s = 0.f;
  #pragma unroll
  for (int i = 0; i < 32; ++i) s += v[i];
  s += __shfl_xor(s, 1);
  s += __shfl_xor(s, 2);                           // 4 lanes per row
  if ((tid & 3) == 0) dvr[r] = 1.0f / sqrtf(s);
  __syncthreads();

  const float dr = dvr[r];
  ushort* dst = Hn + (size_t)bc * 16384 + (size_t)r * 128 + q0;
  #pragma unroll
  for (int i = 0; i < 8; ++i) {
    float4 dc = *(const float4*)&dvr[q0 + i * 4];
    ushort4 o;
    o.x = f2bf(v[i * 4 + 0] * dr * dc.x);
    o.y = f2bf(v[i * 4 + 1] * dr * dc.y);
    o.z = f2bf(v[i * 4 + 2] * dr * dc.z);
    o.w = f2bf(v[i * 4 + 3] * dr * dc.w);
    *(ushort4*)&dst[i * 4] = o;
  }
}

// ---------------- gcn_conv GEMM + leaky + soft-sum -> XcT[b*256+t][n] bf16 ----------------
__global__ __launch_bounds__(256, 2) void k_conv2(
    const float* __restrict__ X, const ushort* __restrict__ Hn,
    const float* __restrict__ wscal, const float* __restrict__ soft,
    ushort* __restrict__ XcT) {
  __shared__ ushort hc[N_][136];       // one channel's Hn tile
  __shared__ ushort xt[N_][136];       // X^T[f][m] one f-half; reused as out staging
  const int b = blockIdx.x;
  const int tid = threadIdx.x;
  const int lane = tid & 63, w = tid >> 6;
  const int rq = lane >> 4, l15 = lane & 15;
  const float wmul = wscal[0];
  const float scf[3] = {soft[0], soft[1], soft[2]};
  const ushort* Hb = Hn + (size_t)b * C_ * N_ * N_;
  const int srow = tid >> 1;                   // staging: row, col-half
  const int scol = (tid & 1) * 64;

  for (int fh = 0; fh < 2; ++fh) {
    __syncthreads();
    {
      const int fl4 = (tid & 31) * 4;
      const int mof = tid >> 5;
      #pragma unroll
      for (int p = 0; p < 16; ++p) {
        int m = p * 8 + mof;
        float4 v = *(const float4*)&X[((size_t)b * N_ + m) * F_ + fh * 128 + fl4];
        xt[fl4 + 0][m] = f2bf(v.x);
        xt[fl4 + 1][m] = f2bf(v.y);
        xt[fl4 + 2][m] = f2bf(v.z);
        xt[fl4 + 3][m] = f2bf(v.w);
      }
    }
    __syncthreads();

    s8v af[2][4];
    #pragma unroll
    for (int rt = 0; rt < 2; ++rt)
      #pragma unroll
      for (int kk = 0; kk < 4; ++kk)
        af[rt][kk] = *(const s8v*)&xt[w * 32 + rt * 16 + l15][kk * 32 + rq * 8];

    f4v xc[2][8];
    #pragma unroll
    for (int rt = 0; rt < 2; ++rt)
      #pragma unroll
      for (int nt = 0; nt < 8; ++nt)
        xc[rt][nt] = (f4v){0.f, 0.f, 0.f, 0.f};

    for (int c = 0; c < C_; ++c) {
      __syncthreads();
      {
        const ushort* hsrc = &Hb[((size_t)c * N_ + srow) * N_ + scol];
        #pragma unroll
        for (int p = 0; p < 8; ++p)
          *(s8v*)&hc[srow][scol + p * 8] = *(const s8v*)&hsrc[p * 8];
      }
      __syncthreads();

      f4v hx[2][8];
      #pragma unroll
      for (int rt = 0; rt < 2; ++rt)
        #pragma unroll
        for (int nt = 0; nt < 8; ++nt)
          hx[rt][nt] = (f4v){0.f, 0.f, 0.f, 0.f};
      #pragma unroll
      for (int kk = 0; kk < 4; ++kk) {
        #pragma unroll
        for (int nt = 0; nt < 8; ++nt) {
          s8v bf = *(const s8v*)&hc[nt * 16 + l15][kk * 32 + rq * 8];
          hx[0][nt] = __builtin_amdgcn_mfma_f32_16x16x32_bf16(af[0][kk], bf, hx[0][nt], 0, 0, 0);
          hx[1][nt] = __builtin_amdgcn_mfma_f32_16x16x32_bf16(af[1][kk], bf, hx[1][nt], 0, 0, 0);
        }
      }
      const float s = scf[c];
      #pragma unroll
      for (int nt = 0; nt < 8; ++nt) {
        #pragma unroll
        for (int i = 0; i < 4; ++i) {
          float v0 = hx[0][nt][i] * wmul;
          xc[0][nt][i] += s * fmaxf(v0, 0.01f * v0);
          float v1 = hx[1][nt][i] * wmul;
          xc[1][nt][i] += s * fmaxf(v1, 0.01f * v1);
        }
      }
    }
    __syncthreads();
    #pragma unroll
    for (int rt = 0; rt < 2; ++rt)
      #pragma unroll
      for (int nt = 0; nt < 8; ++nt)
        #pragma unroll
        for (int i = 0; i < 4; ++i)
          xt[w * 32 + rt * 16 + rq * 4 + i][nt * 16 + l15] = f2bf(xc[rt][nt][i]);
    __syncthreads();
    #pragma unroll
    for (int p = 0; p < 4; ++p) {
      int tl = p * 32 + (tid >> 3);
      int n0 = (tid & 7) * 16;
      size_t rowb = ((size_t)b * F_ + fh * 128 + tl) * N_;
      *(s8v*)&XcT[rowb + n0]     = *(const s8v*)&xt[tl][n0];
      *(s8v*)&XcT[rowb + n0 + 8] = *(const s8v*)&xt[tl][n0 + 8];
    }
  }
}

// ---------------- bidirectional GRU (proven structure, bf16 weight buffer) ----------------
__global__ __launch_bounds__(512, 2) void k_gru(
    const ushort* __restrict__ XcT, const ushort* __restrict__ wbf,
    const float* __restrict__ bihf, const float* __restrict__ bhhf,
    const float* __restrict__ bihb, const float* __restrict__ bhhb,
    ushort* __restrict__ y) {
  __shared__ ushort hlds[2][16][136];
  __shared__ ushort xbuf[2][16][136];
  const int dir = blockIdx.x >> 5;
  const int chunk = blockIdx.x & 31;
  const int tid = threadIdx.x;
  const int lane = tid & 63, w = tid >> 6;
  const int rq = lane >> 4, l15 = lane & 15;
  const int jb = w * 16;
  const int jr = jb + rq * 4;
  const ushort* wih = wbf + (size_t)(dir * 2) * G3_ * HID_;
  const ushort* whh = wih + G3_ * HID_;
  const float* bih = dir ? bihb : bihf;
  const float* bhh = dir ? bhhb : bhhf;

  s8v fir[4], fiz[4], fin[4], fhr[4], fhz[4], fhn[4];
  #pragma unroll
  for (int kk = 0; kk < 4; ++kk) {
    const int ko = kk * 32 + rq * 8;
    const int row = jb + l15;
    fir[kk] = *(const s8v*)&wih[(size_t)(row)       * HID_ + ko];
    fiz[kk] = *(const s8v*)&wih[(size_t)(128 + row) * HID_ + ko];
    fin[kk] = *(const s8v*)&wih[(size_t)(256 + row) * HID_ + ko];
    fhr[kk] = *(const s8v*)&whh[(size_t)(row)       * HID_ + ko];
    fhz[kk] = *(const s8v*)&whh[(size_t)(128 + row) * HID_ + ko];
    fhn[kk] = *(const s8v*)&whh[(size_t)(256 + row) * HID_ + ko];
  }
  float4 bi_r = *(const float4*)&bih[jr],        bh_r = *(const float4*)&bhh[jr];
  float4 bi_z = *(const float4*)&bih[128 + jr],  bh_z = *(const float4*)&bhh[128 + jr];
  float4 bin4 = *(const float4*)&bih[256 + jr];
  float4 bhn4 = *(const float4*)&bhh[256 + jr];
  f4v br = {bi_r.x + bh_r.x, bi_r.y + bh_r.y, bi_r.z + bh_r.z, bi_r.w + bh_r.w};
  f4v bz = {bi_z.x + bh_z.x, bi_z.y + bh_z.y, bi_z.z + bh_z.z, bi_z.w + bh_z.w};
  f4v bin = {bin4.x, bin4.y, bin4.z, bin4.w};
  f4v bhn = {bhn4.x, bhn4.y, bhn4.z, bhn4.w};

  for (int i = tid; i < 16 * 136; i += 512) ((ushort*)hlds[0])[i] = 0;

  const int rr = tid >> 5;
  const int nq = (tid & 31) * 4;
  const size_t xrow = (size_t)(chunk * 16 + rr) * T_;
  {
    int t0 = dir ? (T_ - 1) : 0;
    *(ushort4*)&xbuf[0][rr][nq] = *(const ushort4*)&XcT[(xrow + t0) * N_ + nq];
  }
  f4v hreg = {0.f, 0.f, 0.f, 0.f};
  __syncthreads();

  for (int s = 0; s < T_; ++s) {
    const int cur = s & 1;
    const int t_in = dir ? (T_ - 1 - s) : s;
    const int sn = (s + 1 < T_) ? s + 1 : s;
    const int t_nx = dir ? (T_ - 1 - sn) : sn;
    ushort4 xn = *(const ushort4*)&XcT[(xrow + t_nx) * N_ + nq];

    f4v ar = br, az = bz, ain = bin, ahn = bhn;
    #pragma unroll
    for (int kk = 0; kk < 4; ++kk) {
      const int ko = kk * 32 + rq * 8;
      s8v xf = *(const s8v*)&xbuf[cur][l15][ko];
      s8v hf = *(const s8v*)&hlds[cur][l15][ko];
      ar  = __builtin_amdgcn_mfma_f32_16x16x32_bf16(fir[kk], xf, ar, 0, 0, 0);
      ar  = __builtin_amdgcn_mfma_f32_16x16x32_bf16(fhr[kk], hf, ar, 0, 0, 0);
      az  = __builtin_amdgcn_mfma_f32_16x16x32_bf16(fiz[kk], xf, az, 0, 0, 0);
      az  = __builtin_amdgcn_mfma_f32_16x16x32_bf16(fhz[kk], hf, az, 0, 0, 0);
      ain = __builtin_amdgcn_mfma_f32_16x16x32_bf16(fin[kk], xf, ain, 0, 0, 0);
      ahn = __builtin_amdgcn_mfma_f32_16x16x32_bf16(fhn[kk], hf, ahn, 0, 0, 0);
    }
    ushort hb[4];
    #pragma unroll
    for (int i = 0; i < 4; ++i) {
      float r = sigm(ar[i]);
      float z = sigm(az[i]);
      float n = tanh_(ain[i] + r * ahn[i]);
      float h = n + z * (hreg[i] - n);
      hreg[i] = h;
      hb[i] = f2bf(h);
    }
    ushort4 hv; hv.x = hb[0]; hv.y = hb[1]; hv.z = hb[2]; hv.w = hb[3];
    *(ushort4*)&y[((size_t)t_in * B_ + chunk * 16 + l15) * 256 + dir * 128 + jr] = hv;
    *(ushort4*)&hlds[cur ^ 1][l15][jr] = hv;
    *(ushort4*)&xbuf[cur ^ 1][rr][nq] = xn;
    LDS_BARRIER();
  }
}

// ---------------- BN stats per t-channel over (b,j): fold gamma/beta ----------------
__global__ void k_stats(const ushort* __restrict__ y, const float* __restrict__ gamma,
                        const float* __restrict__ beta, float* __restrict__ stats) {
  const int t = blockIdx.x, tid = threadIdx.x;
  const ushort* p = y + (size_t)t * 256 * B_;
  float s = 0.f, q = 0.f;
  for (int i = tid * 8; i < 256 * B_; i += 256 * 8) {
    s8v v = *(const s8v*)&p[i];
    #pragma unroll
    for (int e = 0; e < 8; ++e) {
      float f = bf2f((ushort)v[e]);
      s += f; q += f * f;
    }
  }
  #pragma unroll
  for (int o = 32; o; o >>= 1) { s += __shfl_xor(s, o); q += __shfl_xor(q, o); }
  __shared__ float rs[4], rq2[4];
  if ((tid & 63) == 0) { rs[tid >> 6] = s; rq2[tid >> 6] = q; }
  __syncthreads();
  if (tid == 0) {
    s = rs[0] + rs[1] + rs[2] + rs[3];
    q = rq2[0] + rq2[1] + rq2[2] + rq2[3];
    const float inv = 1.0f / (256.f * 512.f);
    float mean = s * inv;
    float var = q * inv - mean * mean;
    float istd = 1.0f / sqrtf(var + 1e-5f);
    float a = gamma[t] * istd;
    stats[2 * t] = a;
    stats[2 * t + 1] = beta[t] - mean * a;
  }
}

// ---------------- BN apply + transpose: y[t][b][j] -> out[b][j][t] fp32 ----------------
// block = (b, 64-t tile). Reads 512B contiguous per t-row; writes 256B contiguous t-chunks.
__global__ __launch_bounds__(256) void k_apply(
    const ushort* __restrict__ y, const float* __restrict__ stats,
    float* __restrict__ out) {
  __shared__ ushort tile[64][258];     // [t_local][j], +2 pad
  __shared__ float sA[64], sB[64];
  const int b = blockIdx.x;
  const int t0 = blockIdx.y * 64;
  const int tid = threadIdx.x;
  if (tid < 64) {
    sA[tid] = stats[2 * (t0 + tid)];
    sB[tid] = stats[2 * (t0 + tid) + 1];
  }
  {
    const int jc = (tid & 31) * 8;
    #pragma unroll
    for (int p = 0; p < 8; ++p) {
      int tl = p * 8 + (tid >> 5);
      *(s8v*)&tile[tl][jc] = *(const s8v*)&y[((size_t)(t0 + tl) * B_ + b) * 256 + jc];
    }
  }
  __syncthreads();
  const int tq = tid & 15;             // t-quad within tile
  const int jo = tid >> 4;             // j offset 0..15
  #pragma unroll
  for (int jb = 0; jb < 256; jb += 16) {
    const int j = jb + jo;
    float4 o;
    o.x = bf2f(tile[tq * 4 + 0][j]) * sA[tq * 4 + 0] + sB[tq * 4 + 0];
    o.y = bf2f(tile[tq * 4 + 1][j]) * sA[tq * 4 + 1] + sB[tq * 4 + 1];
    o.z = bf2f(tile[tq * 4 + 2][j]) * sA[tq * 4 + 2] + sB[tq * 4 + 2];
    o.w = bf2f(tile[tq * 4 + 3][j]) * sA[tq * 4 + 3] + sB[tq * 4 + 3];
    *(float4*)&out[((size_t)b * 256 + j) * 256 + t0 + tq * 4] = o;
  }
}

extern "C" void kernel_launch(void* const* d_in, const int* in_sizes, int n_in,
                              void* d_out, int out_size, void* d_ws, size_t ws_size,
                              hipStream_t stream) {
  const float* X      = (const float*)d_in[0];
  const float* H      = (const float*)d_in[1];
  const float* weight = (const float*)d_in[2];
  const float* soft   = (const float*)d_in[3];
  const float* w_ih_f = (const float*)d_in[4];
  const float* w_hh_f = (const float*)d_in[5];
  const float* b_ih_f = (const float*)d_in[6];
  const float* b_hh_f = (const float*)d_in[7];
  const float* w_ih_b = (const float*)d_in[8];
  const float* w_hh_b = (const float*)d_in[9];
  const float* b_ih_b = (const float*)d_in[10];
  const float* b_hh_b = (const float*)d_in[11];
  const float* gamma  = (const float*)d_in[12];
  const float* beta   = (const float*)d_in[13];
  float* out = (float*)d_out;

  char* ws = (char*)d_ws;
  ushort* wbf   = (ushort*)(ws);                        // 393,216 B
  ushort* Hnb   = (ushort*)(ws + 393216);               // 50,331,648 B
  ushort* XcT   = (ushort*)(ws + 50724864);             // 33,554,432 B
  ushort* ybuf  = (ushort*)(ws + 84279296);             // 67,108,864 B  [t][b][j]
  float*  stats = (float*) (ws + 151388160);            // 2,048 B

  k_wcvt<<<768, 256, 0, stream>>>(w_ih_f, w_hh_f, w_ih_b, w_hh_b, wbf);
  k_hnorm<<<B_ * C_, 512, 0, stream>>>(H, Hnb);
  k_conv2<<<B_, 256, 0, stream>>>(X, Hnb, weight, soft, XcT);
  k_gru<<<64, 512, 0, stream>>>(XcT, wbf, b_ih_f, b_hh_f, b_ih_b, b_hh_b, ybuf);
  k_stats<<<T_, 256, 0, stream>>>(ybuf, gamma, beta, stats);
  k_apply<<<dim3(512, 4), 256, 0, stream>>>(ybuf, stats, out);
}